// Round 10
// baseline (30994.376 us; speedup 1.0000x reference)
//
#include <hip/hip_runtime.h>
#include <hip/hip_bf16.h>
#include <hip/hip_fp16.h>
#include <stdint.h>

typedef unsigned int uint;
typedef unsigned short ushort;

#define TPB 768

// ---------------- ws layout (ushorts = f16) ----------------
// pack: ws[base + (kb*ROWS + j)*8 + kl] = f16(W[j][kb*8+kl]); uint4 load at
// (kb*ROWS+j) -> 8 consecutive-k weights of row j. A0 packed over FULL k=256
// (k<128 = x-part, used by xp_kernel; k>=128 = l_read part, used in-scan).
#define OFF_A0 0
#define OFF_A1 (768*256)
#define OFF_A2 (2*768*256)
#define OFF_A3 (3*768*256)
#define OFF_A4 (4*768*256)
#define WS_USHORTS (4*768*256 + 320*256)    // 868352
#define WB_BYTES ((size_t)WS_USHORTS * 2)   // 1736704
#define GIXP_FLOATS ((size_t)64*512*768)    // 100.7 MB fp32

__device__ __forceinline__ __half2 h2cast(uint u){
    union { uint u; __half2 h; } c; c.u = u; return c.h;
}
__device__ __forceinline__ float sigm(float x){ return 1.0f / (1.0f + __expf(-x)); }
__device__ __forceinline__ float tanh_(float x){
    float xc = fminf(fmaxf(x, -15.0f), 15.0f);
    float e  = __expf(2.0f * xc);
    return (e - 1.0f) / (e + 1.0f);
}

// ---------------- prep: transpose+pack+f16 all weights ----------------
__global__ void prep_kernel(const float* __restrict__ Wih0, const float* __restrict__ Whh0,
                            const float* __restrict__ Wih1, const float* __restrict__ Whh1,
                            const float* __restrict__ Wint, ushort* __restrict__ ws)
{
    int idx = blockIdx.x * 256 + threadIdx.x;
    if (idx >= WS_USHORTS) return;
    const float* src; int rows; int base; int p;
    if (idx < 4*768*256) {
        int m = idx / (768*256); p = idx % (768*256);
        src  = (m==0) ? Wih0 : (m==1) ? Whh0 : (m==2) ? Wih1 : Whh1;
        rows = 768; base = m * (768*256);
    } else {
        p = idx - 4*768*256; src = Wint; rows = 320; base = 4*768*256;
    }
    int kb  = p / (rows*8);
    int rem = p - kb*(rows*8);
    int j   = rem >> 3;
    int kl  = rem & 7;
    int k   = kb*8 + kl;
    __half h = __float2half_rn(src[j*256 + k]);
    ws[base + p] = *reinterpret_cast<ushort*>(&h);
}

// ---------------- xp: gixp[b][t][j] = b_ih0[j] + W_ih0[j, :128] @ x[b,t,:] ----
__global__ __launch_bounds__(256) void xp_kernel(const float* __restrict__ x,
        const float* __restrict__ bih0, const ushort* __restrict__ ws,
        float* __restrict__ gixp)
{
    __shared__ float xs[32][132];
    __shared__ float ys[32][129];
    const int tid = threadIdx.x;
    const int b   = blockIdx.x >> 4;
    const int t0  = (blockIdx.x & 15) * 32;
    for (int i = tid; i < 32*32; i += 256) {
        int t = i >> 5, kq = i & 31;
        *(float4*)&xs[t][kq*4] = *(const float4*)&x[((size_t)(b*512 + t0 + t))*128 + kq*4];
    }
    __syncthreads();
    const int rg = tid >> 5;       // 0..7 -> row group of 96
    const int t  = tid & 31;
    float xr[128];
#pragma unroll
    for (int kq = 0; kq < 32; ++kq) {
        float4 f = *(const float4*)&xs[t][kq*4];
        xr[kq*4+0]=f.x; xr[kq*4+1]=f.y; xr[kq*4+2]=f.z; xr[kq*4+3]=f.w;
    }
    const uint4* P = (const uint4*)ws;   // OFF_A0, kb<16 = x-part
#pragma unroll 1
    for (int rc = 0; rc < 6; ++rc) {
        __syncthreads();   // previous rc's ys store loop done
#pragma unroll 1
        for (int s = 0; s < 16; ++s) {
            int j = rg*96 + rc*16 + s;
            float pa = bih0[j], pb = 0.f;
#pragma unroll
            for (int kb = 0; kb < 16; ++kb) {
                uint4 w = P[kb*768 + j];
                __half2 h;
                h=h2cast(w.x); pa += __low2float(h)*xr[kb*8+0]; pa += __high2float(h)*xr[kb*8+1];
                h=h2cast(w.y); pa += __low2float(h)*xr[kb*8+2]; pa += __high2float(h)*xr[kb*8+3];
                h=h2cast(w.z); pb += __low2float(h)*xr[kb*8+4]; pb += __high2float(h)*xr[kb*8+5];
                h=h2cast(w.w); pb += __low2float(h)*xr[kb*8+6]; pb += __high2float(h)*xr[kb*8+7];
            }
            ys[t][rg*16 + s] = pa + pb;
        }
        __syncthreads();
        for (int i2 = tid; i2 < 32*128; i2 += 256) {
            int t2 = i2 >> 7, c = i2 & 127;
            int j  = (c >> 4)*96 + rc*16 + (c & 15);
            gixp[((size_t)(b*512 + t0 + t2))*768 + j] = ys[t2][c];
        }
    }
}

// 8 mixed-precision FMAs for one uint4 pair against shared input slices
#define FMA8(W0, W1, KB) { \
    float4 va = *(const float4*)&vin[(KB)*8]; \
    float4 vb = *(const float4*)&vin[(KB)*8 + 4]; \
    __half2 h; \
    h=h2cast((W0).x); p0 += __low2float(h)*va.x; p0 += __high2float(h)*va.y; \
    h=h2cast((W0).y); p0 += __low2float(h)*va.z; p0 += __high2float(h)*va.w; \
    h=h2cast((W0).z); q0 += __low2float(h)*vb.x; q0 += __high2float(h)*vb.y; \
    h=h2cast((W0).w); q0 += __low2float(h)*vb.z; q0 += __high2float(h)*vb.w; \
    h=h2cast((W1).x); p1 += __low2float(h)*va.x; p1 += __high2float(h)*va.y; \
    h=h2cast((W1).y); p1 += __low2float(h)*va.z; p1 += __high2float(h)*va.w; \
    h=h2cast((W1).z); q1 += __low2float(h)*vb.x; q1 += __high2float(h)*vb.y; \
    h=h2cast((W1).w); q1 += __low2float(h)*vb.z; q1 += __high2float(h)*vb.w; }

// two rows (j0,j1) of the same matrix vs one shared vector; explicit
// double-buffered prefetch: next 4-kb chunk loads issued before current FMAs.
template<int ROWS, int NKB>
__device__ __forceinline__ void mv2_pipe(const ushort* __restrict__ W, const float* vin,
                                         float b0, float b1, float* o0, float* o1,
                                         int j0, int j1)
{
    const uint4* P = (const uint4*)W;
    float p0 = b0, q0 = 0.f, p1 = b1, q1 = 0.f;
    uint4 c0[4], c1[4];
#pragma unroll
    for (int u = 0; u < 4; ++u) { c0[u] = P[u*ROWS + j0]; c1[u] = P[u*ROWS + j1]; }
#pragma unroll
    for (int ch = 0; ch < NKB/4; ++ch) {
        uint4 n0[4], n1[4];
        if (ch + 1 < NKB/4) {
#pragma unroll
            for (int u = 0; u < 4; ++u) {
                n0[u] = P[((ch+1)*4 + u)*ROWS + j0];
                n1[u] = P[((ch+1)*4 + u)*ROWS + j1];
            }
        }
#pragma unroll
        for (int u = 0; u < 4; ++u) { FMA8(c0[u], c1[u], ch*4 + u); }
        if (ch + 1 < NKB/4) {
#pragma unroll
            for (int u = 0; u < 4; ++u) { c0[u] = n0[u]; c1[u] = n1[u]; }
        }
    }
    *o0 = p0 + q0; *o1 = p1 + q1;
}

__global__ __launch_bounds__(TPB) void ebm_main(
    const float* __restrict__ x, const float* __restrict__ h0i,
    const float* __restrict__ b_ih0, const float* __restrict__ b_hh0,
    const float* __restrict__ b_ih1, const float* __restrict__ b_hh1,
    const float* __restrict__ b_int, const float* __restrict__ Wmix,
    const float* __restrict__ bmix,
    const ushort* __restrict__ ws, const float* __restrict__ gixp, int use_xp,
    float* __restrict__ out)
{
    __shared__ float v[256];            // ctl (fallback) or l_read slice (xp)
    __shared__ float gi[768], gh[768];
    __shared__ float h0s[256], h1s[256];
    __shared__ float lread[128];
    __shared__ float em[64][33], bm[64][33];
    __shared__ float itf[320];
    __shared__ float minv_em[64], minv_bm[64], kinv[8];
    __shared__ float sc[8][64];
    __shared__ float wwv[64], ev[32], emer[32];
    __shared__ float emrd[4][32], bmrd[4][32];
    __shared__ float wmix_s[32][65];

    const int tid = threadIdx.x;
    const int b   = blockIdx.x;

    if (tid < 256) { h0s[tid] = h0i[b*256 + tid]; h1s[tid] = h0i[(64 + b)*256 + tid]; }
    for (int i = tid; i < 64*33; i += TPB) { (&em[0][0])[i] = 0.f; (&bm[0][0])[i] = 0.f; }
    if (tid < 128) lread[tid] = 0.f;
    for (int i = tid; i < 32*64; i += TPB) { wmix_s[i >> 6][i & 63] = Wmix[i]; }
    __syncthreads();

    for (int t = 0; t < 512; ++t) {
        const size_t outbase = ((size_t)b*512 + t) * 640;

        // ---- inputs for layer0 ----
        if (use_xp) {
            gi[tid] = gixp[((size_t)(b*512 + t))*768 + tid];  // bias + x-part
            if (tid < 128) v[tid] = lread[tid];
        } else {
            if (tid < 128)      v[tid] = x[((size_t)b*512 + t)*128 + tid];
            else if (tid < 256) v[tid] = lread[tid - 128];
        }
        __syncthreads();

        // ---- GRU layer 0 ----
        if (tid < 384) {
            if (use_xp) {
                float bb0 = gi[tid], bb1 = gi[tid + 384];
                mv2_pipe<768,16>(ws + OFF_A0 + 16*768*8, v, bb0, bb1,
                                 &gi[tid], &gi[tid + 384], tid, tid + 384);
            } else {
                mv2_pipe<768,32>(ws + OFF_A0, v, b_ih0[tid], b_ih0[tid + 384],
                                 &gi[tid], &gi[tid + 384], tid, tid + 384);
            }
        } else {
            int i = tid - 384;
            mv2_pipe<768,32>(ws + OFF_A1, h0s, b_hh0[i], b_hh0[i + 384],
                             &gh[i], &gh[i + 384], i, i + 384);
        }
        __syncthreads();
        if (tid < 256) {
            float r  = sigm(gi[tid]       + gh[tid]);
            float z  = sigm(gi[256 + tid] + gh[256 + tid]);
            float n  = tanh_(gi[512 + tid] + r * gh[512 + tid]);
            float hn = (1.f - z) * n + z * h0s[tid];
            h0s[tid] = hn;
            out[outbase + tid] = hn;
        }
        __syncthreads();

        // ---- GRU layer 1 ----
        if (tid < 384) {
            mv2_pipe<768,32>(ws + OFF_A2, h0s, b_ih1[tid], b_ih1[tid + 384],
                             &gi[tid], &gi[tid + 384], tid, tid + 384);
        } else {
            int i = tid - 384;
            mv2_pipe<768,32>(ws + OFF_A3, h1s, b_hh1[i], b_hh1[i + 384],
                             &gh[i], &gh[i + 384], i, i + 384);
        }
        __syncthreads();
        if (tid < 256) {
            float r  = sigm(gi[tid]       + gh[tid]);
            float z  = sigm(gi[256 + tid] + gh[256 + tid]);
            float n  = tanh_(gi[512 + tid] + r * gh[512 + tid]);
            float hn = (1.f - z) * n + z * h1s[tid];
            h1s[tid] = hn;
            out[outbase + 256 + tid] = hn;
        }
        __syncthreads();

        // ---- interface matvec + (hoisted) em/bm row norms on idle threads ----
        const int slot = t & 63;
        if (tid < 160) {
            float a0, a1;
            mv2_pipe<320,32>(ws + OFF_A4, h1s, b_int[tid], b_int[tid + 160],
                             &a0, &a1, tid, tid + 160);
            itf[tid]       = fminf(fmaxf(a0, 0.f), 20.f);
            itf[tid + 160] = fminf(fmaxf(a1, 0.f), 20.f);
        } else if (tid >= 320 && tid < 384) {
            int n = tid - 320; float s = 0.f;      // em norms on OLD em (slot fixed later)
#pragma unroll
            for (int w2 = 0; w2 < 32; ++w2) { float q = em[n][w2]; s += q*q; }
            minv_em[n] = 1.f / (sqrtf(s) + 1e-8f);
        } else if (tid >= 384 && tid < 448) {
            int n = tid - 384; float s = 0.f;
#pragma unroll
            for (int w2 = 0; w2 < 32; ++w2) { float q = bm[n][w2]; s += q*q; }
            minv_bm[n] = 1.f / (sqrtf(s) + 1e-8f);
        }
        __syncthreads();

        // ---- em slot write, erase vector, key norms ----
        if (tid < 32) {
            emer[tid] = em[slot][tid];
            em[slot][tid] = itf[256 + tid];
            ev[tid] = sigm(itf[288 + tid]);
        } else if (tid < 40) {
            int r = tid - 32;
            const float* kk = &itf[r*32];
            float s = 0.f;
#pragma unroll
            for (int w2 = 0; w2 < 32; ++w2) { float q = kk[w2]; s += q*q; }
            kinv[r] = 1.f / (sqrtf(s) + 1e-8f);
        }
        __syncthreads();

        // ---- cosine scores (slot row's norm recomputed inline on NEW em) ----
        if (tid < 512) {
            int mm = tid >> 8, r = (tid >> 6) & 3, n = tid & 63;
            const float* kk = &itf[mm*128 + r*32];
            const float (*M)[33] = mm ? bm : em;
            float d = 0.f, ss = 0.f;
#pragma unroll
            for (int w2 = 0; w2 < 32; ++w2) { float m_ = M[n][w2]; d += kk[w2]*m_; ss += m_*m_; }
            float minv = mm ? minv_bm[n]
                            : ((n == slot) ? 1.f/(sqrtf(ss) + 1e-8f) : minv_em[n]);
            float val = d * kinv[mm*4 + r] * minv;
            if (!mm) val *= (1.f/0.3f);
            sc[mm*4 + r][n] = val;
        }
        __syncthreads();

        // ---- softmax over 64 slots ----
        {
            int wave = tid >> 6, lane = tid & 63;
            if (wave < 8) {
                float val = sc[wave][lane];
                float m = val;
                for (int o = 32; o > 0; o >>= 1) m = fmaxf(m, __shfl_xor(m, o));
                float e = __expf(val - m);
                float s = e;
                for (int o = 32; o > 0; o >>= 1) s += __shfl_xor(s, o);
                sc[wave][lane] = e / s;
            }
        }
        __syncthreads();

        // ---- ww + weighted reads ----
        if (tid < 64) wwv[tid] = 0.25f * (sc[4][tid] + sc[5][tid] + sc[6][tid] + sc[7][tid]);
        if (tid < 256) {
            int mm = tid >> 7, r = (tid >> 5) & 3, w2 = tid & 31;
            const float (*M)[33] = mm ? bm : em;
            const float* wr = sc[mm*4 + r];
            float a = 0.f;
#pragma unroll 8
            for (int n = 0; n < 64; ++n) a += wr[n] * M[n][w2];
            if (mm) bmrd[r][w2] = a; else emrd[r][w2] = a;
        }
        __syncthreads();

        // ---- mix gate + l_read ; bm update ----
        if (tid < 128) {
            int r = tid >> 5, w2 = tid & 31;
            float a = bmix[w2];
#pragma unroll
            for (int c = 0; c < 32; ++c) a += wmix_s[w2][c]      * emrd[r][c];
#pragma unroll
            for (int c = 0; c < 32; ++c) a += wmix_s[w2][32 + c] * bmrd[r][c];
            float g  = sigm(a);
            float rd = g * emrd[r][w2] + (1.f - g) * bmrd[r][w2];
            lread[tid] = rd;
            out[outbase + 512 + tid] = rd;
        } else {
            for (int i2 = tid - 128; i2 < 2048; i2 += TPB - 128) {
                int n = i2 >> 5, w2 = i2 & 31;
                bm[n][w2] = bm[n][w2] * (1.f - wwv[n]*ev[w2]) + wwv[n]*emer[w2];
            }
        }
        __syncthreads();
    }
}

extern "C" void kernel_launch(void* const* d_in, const int* in_sizes, int n_in,
                              void* d_out, int out_size, void* d_ws, size_t ws_size,
                              hipStream_t stream)
{
    const float* x    = (const float*)d_in[0];
    const float* h0   = (const float*)d_in[1];
    const float* Wih0 = (const float*)d_in[2];
    const float* Whh0 = (const float*)d_in[3];
    const float* bih0 = (const float*)d_in[4];
    const float* bhh0 = (const float*)d_in[5];
    const float* Wih1 = (const float*)d_in[6];
    const float* Whh1 = (const float*)d_in[7];
    const float* bih1 = (const float*)d_in[8];
    const float* bhh1 = (const float*)d_in[9];
    const float* Wint = (const float*)d_in[10];
    const float* bint = (const float*)d_in[11];
    const float* Wmix = (const float*)d_in[12];
    const float* bmix = (const float*)d_in[13];
    ushort* ws  = (ushort*)d_ws;
    float*  out = (float*)d_out;

    if (ws_size < WB_BYTES) return;
    const size_t need_xp = WB_BYTES + GIXP_FLOATS * 4;
    const int use_xp = (ws_size >= need_xp) ? 1 : 0;
    float* gixp = (float*)((char*)d_ws + WB_BYTES);

    prep_kernel<<<(WS_USHORTS + 255)/256, 256, 0, stream>>>(Wih0, Whh0, Wih1, Whh1, Wint, ws);
    if (use_xp)
        xp_kernel<<<64*16, 256, 0, stream>>>(x, bih0, ws, gixp);
    ebm_main<<<64, TPB, 0, stream>>>(x, h0, bih0, bhh0, bih1, bhh1, bint, Wmix, bmix,
                                     ws, gixp, use_xp, out);
}

// Round 11
// 12541.964 us; speedup vs baseline: 2.4713x; 2.4713x over previous
//
#include <hip/hip_runtime.h>
#include <hip/hip_fp16.h>
#include <stdint.h>

typedef unsigned int uint;
typedef unsigned short ushort;

#define TPB 768

// ---------------- ws layout (ushorts = f16) ----------------
// pack: ws[base + (kb*ROWS + j)*8 + kl] = f16(W[j][kb*8+kl]); uint4 load at
// (kb*ROWS + j) -> 8 consecutive-k weights of row j.
#define OFF_A0 0
#define OFF_A1 (768*256)
#define OFF_A2 (2*768*256)
#define OFF_A3 (3*768*256)
#define OFF_A4 (4*768*256)
#define WS_USHORTS (4*768*256 + 320*256)   // 868352

__device__ __forceinline__ __half2 h2cast(uint u){
    union { uint u; __half2 h; } c; c.u = u; return c.h;
}
__device__ __forceinline__ float sigm(float x){ return 1.0f / (1.0f + __expf(-x)); }
__device__ __forceinline__ float tanh_(float x){
    float xc = fminf(fmaxf(x, -15.0f), 15.0f);
    float e  = __expf(2.0f * xc);
    return (e - 1.0f) / (e + 1.0f);
}

// ---------------- prep: transpose+pack+f16 all weights ----------------
__global__ void prep_kernel(const float* __restrict__ Wih0, const float* __restrict__ Whh0,
                            const float* __restrict__ Wih1, const float* __restrict__ Whh1,
                            const float* __restrict__ Wint, ushort* __restrict__ ws)
{
    int idx = blockIdx.x * 256 + threadIdx.x;
    if (idx >= WS_USHORTS) return;
    const float* src; int rows; int base; int p;
    if (idx < 4*768*256) {
        int m = idx / (768*256); p = idx % (768*256);
        src  = (m==0) ? Wih0 : (m==1) ? Whh0 : (m==2) ? Wih1 : Whh1;
        rows = 768; base = m * (768*256);
    } else {
        p = idx - 4*768*256; src = Wint; rows = 320; base = 4*768*256;
    }
    int kb  = p / (rows*8);
    int rem = p - kb*(rows*8);
    int j   = rem >> 3;
    int kl  = rem & 7;
    int k   = kb*8 + kl;
    __half h = __float2half_rn(src[j*256 + k]);
    ws[base + p] = *reinterpret_cast<ushort*>(&h);
}

// dual mat-vec row j: oi = bi + Wi[j,:]@vin ; oh = bh + Wh[j,:]@hin  (f16 weights)
__device__ __forceinline__ void dual_mv(const ushort* __restrict__ Wi, const ushort* __restrict__ Wh,
                                        const float* vin, const float* hin,
                                        float bi, float bh, float* oi, float* oh, int j)
{
    const uint4* Pi = (const uint4*)Wi;
    const uint4* Ph = (const uint4*)Wh;
    float ai = bi, a2 = 0.f, ah = bh, b2 = 0.f;
#pragma unroll 4
    for (int kb = 0; kb < 32; ++kb) {
        uint4 wi = Pi[kb*768 + j];
        uint4 wh = Ph[kb*768 + j];
        float4 va = *(const float4*)&vin[kb*8];
        float4 vb = *(const float4*)&vin[kb*8 + 4];
        float4 ha = *(const float4*)&hin[kb*8];
        float4 hb = *(const float4*)&hin[kb*8 + 4];
        __half2 h;
        h = h2cast(wi.x); ai += __low2float(h)*va.x; ai += __high2float(h)*va.y;
        h = h2cast(wi.y); ai += __low2float(h)*va.z; ai += __high2float(h)*va.w;
        h = h2cast(wi.z); a2 += __low2float(h)*vb.x; a2 += __high2float(h)*vb.y;
        h = h2cast(wi.w); a2 += __low2float(h)*vb.z; a2 += __high2float(h)*vb.w;
        h = h2cast(wh.x); ah += __low2float(h)*ha.x; ah += __high2float(h)*ha.y;
        h = h2cast(wh.y); ah += __low2float(h)*ha.z; ah += __high2float(h)*ha.w;
        h = h2cast(wh.z); b2 += __low2float(h)*hb.x; b2 += __high2float(h)*hb.y;
        h = h2cast(wh.w); b2 += __low2float(h)*hb.z; b2 += __high2float(h)*hb.w;
    }
    *oi = ai + a2; *oh = ah + b2;
}

// single mat-vec row (interface, ROWS=320)
__device__ __forceinline__ float mv1(const ushort* __restrict__ W, const float* vin,
                                     float b0, int j)
{
    const uint4* P = (const uint4*)W;
    float p0 = b0, q0 = 0.f;
#pragma unroll 4
    for (int kb = 0; kb < 32; ++kb) {
        uint4 w = P[kb*320 + j];
        float4 va = *(const float4*)&vin[kb*8];
        float4 vb = *(const float4*)&vin[kb*8 + 4];
        __half2 h;
        h = h2cast(w.x); p0 += __low2float(h)*va.x; p0 += __high2float(h)*va.y;
        h = h2cast(w.y); p0 += __low2float(h)*va.z; p0 += __high2float(h)*va.w;
        h = h2cast(w.z); q0 += __low2float(h)*vb.x; q0 += __high2float(h)*vb.y;
        h = h2cast(w.w); q0 += __low2float(h)*vb.z; q0 += __high2float(h)*vb.w;
    }
    return p0 + q0;
}

__global__ __launch_bounds__(TPB) void ebm_main(
    const float* __restrict__ x, const float* __restrict__ h0i,
    const float* __restrict__ b_ih0, const float* __restrict__ b_hh0,
    const float* __restrict__ b_ih1, const float* __restrict__ b_hh1,
    const float* __restrict__ b_int, const float* __restrict__ Wmix,
    const float* __restrict__ bmix,
    const ushort* __restrict__ ws, float* __restrict__ out)
{
    __shared__ float v[256];                  // ctl = [x_t, l_read]  (built in prev step's tail)
    __shared__ float gi[768], gh[768];
    __shared__ float h0s[256], h1s[256];
    __shared__ float em[64][33], bm[64][33];  // +1 pad
    __shared__ float itf[320];
    __shared__ float minv_em[64], minv_bm[64];
    __shared__ float sc[8][64];
    __shared__ float ev[32], emer[32];
    __shared__ float emrd[4][32], bmrd[4][32];
    __shared__ float wmix_s[32][65];

    const int tid = threadIdx.x;
    const int b   = blockIdx.x;

    // ---- init ----
    if (tid < 256) { h0s[tid] = h0i[b*256 + tid]; h1s[tid] = h0i[(64 + b)*256 + tid]; }
    for (int i = tid; i < 64*33; i += TPB) { (&em[0][0])[i] = 0.f; (&bm[0][0])[i] = 0.f; }
    if (tid < 128)      v[128 + tid] = 0.f;                       // l_read(0) = 0
    else if (tid < 256) v[tid - 128] = x[((size_t)b*512)*128 + (tid - 128)];
    for (int i = tid; i < 32*64; i += TPB) wmix_s[i >> 6][i & 63] = Wmix[i];
    __syncthreads();

    for (int t = 0; t < 512; ++t) {
        const size_t outbase = ((size_t)b*512 + t) * 640;
        const int slot = t & 63;

        // ---- phase 1: GRU layer-0 dual mat-vec (all 768 threads) ----
        dual_mv(ws + OFF_A0, ws + OFF_A1, v, h0s, b_ih0[tid], b_hh0[tid], &gi[tid], &gh[tid], tid);
        __syncthreads();                                           // B1

        // ---- phase 2: gate 0 ----
        if (tid < 256) {
            float r  = sigm(gi[tid]       + gh[tid]);
            float z  = sigm(gi[256 + tid] + gh[256 + tid]);
            float n  = tanh_(gi[512 + tid] + r * gh[512 + tid]);
            float hn = (1.f - z) * n + z * h0s[tid];
            h0s[tid] = hn;
            out[outbase + tid] = hn;
        }
        __syncthreads();                                           // B2

        // ---- phase 3: GRU layer-1 dual mat-vec ----
        dual_mv(ws + OFF_A2, ws + OFF_A3, h0s, h1s, b_ih1[tid], b_hh1[tid], &gi[tid], &gh[tid], tid);
        __syncthreads();                                           // B3

        // ---- phase 4: gate 1 ----
        if (tid < 256) {
            float r  = sigm(gi[tid]       + gh[tid]);
            float z  = sigm(gi[256 + tid] + gh[256 + tid]);
            float n  = tanh_(gi[512 + tid] + r * gh[512 + tid]);
            float hn = (1.f - z) * n + z * h1s[tid];
            h1s[tid] = hn;
            out[outbase + 256 + tid] = hn;
        }
        __syncthreads();                                           // B4

        // ---- phase 5: interface mat-vec (320 thr) + em/bm row norms on idle thr ----
        // norms use em/bm state BEFORE this step's writes; slot row handled inline later.
        if (tid < 320) {
            float a = mv1(ws + OFF_A4, h1s, b_int[tid], tid);
            itf[tid] = fminf(fmaxf(a, 0.f), 20.f);
        } else if (tid < 384) {
            int n = tid - 320; float s = 0.f;
#pragma unroll
            for (int w2 = 0; w2 < 32; ++w2) { float q = em[n][w2]; s += q*q; }
            minv_em[n] = 1.f / (sqrtf(s) + 1e-8f);
        } else if (tid < 448) {
            int n = tid - 384; float s = 0.f;
#pragma unroll
            for (int w2 = 0; w2 < 32; ++w2) { float q = bm[n][w2]; s += q*q; }
            minv_bm[n] = 1.f / (sqrtf(s) + 1e-8f);
        }
        __syncthreads();                                           // B5

        // ---- phase 6: scores + softmax + weighted reads — all in-wave, NO barrier.
        // em's written slot is substituted from itf (write itself deferred to phase 7).
        if (tid < 512) {
            const int row = tid >> 6;          // 0..3 em, 4..7 bm
            const int mm  = row >> 2;
            const int n   = tid & 63;
            const float* kk = &itf[mm*128 + (row & 3)*32];
            float ks = 0.f;
#pragma unroll
            for (int w2 = 0; w2 < 32; ++w2) ks += kk[w2]*kk[w2];   // per-lane key norm
            const float kinv = 1.f / (sqrtf(ks) + 1e-8f);
            float d, minv;
            if (mm == 0 && n == slot) {
                float dd = 0.f, ss = 0.f;
#pragma unroll
                for (int w2 = 0; w2 < 32; ++w2) { float m_ = itf[256 + w2]; dd += kk[w2]*m_; ss += m_*m_; }
                d = dd; minv = 1.f / (sqrtf(ss) + 1e-8f);
            } else {
                const float (*M)[33] = mm ? bm : em;
                float dd = 0.f;
#pragma unroll
                for (int w2 = 0; w2 < 32; ++w2) dd += kk[w2] * M[n][w2];
                d = dd; minv = mm ? minv_bm[n] : minv_em[n];
            }
            float val = d * kinv * minv;
            if (!mm) val *= (1.f/0.3f);
            float m = val;
            for (int o = 32; o > 0; o >>= 1) m = fmaxf(m, __shfl_xor(m, o));
            float e = __expf(val - m);
            float s = e;
            for (int o = 32; o > 0; o >>= 1) s += __shfl_xor(s, o);
            sc[row][n] = e / s;                // in-wave write; read below by same wave
            if (n < 32) {                      // weighted read: lane w2 sums its column
                const int w2 = n;
                float a = 0.f;
#pragma unroll 8
                for (int nn = 0; nn < 64; ++nn) {
                    float m_ = mm ? bm[nn][w2]
                                  : ((nn == slot) ? itf[256 + w2] : em[nn][w2]);
                    a += sc[row][nn] * m_;
                }
                if (mm) bmrd[row & 3][w2] = a; else emrd[row & 3][w2] = a;
            }
        } else if (tid < 544) {                // capture em_erased (old slot row)
            emer[tid - 512] = em[slot][tid - 512];
        } else if (tid < 576) {                // erase gate
            ev[tid - 544] = sigm(itf[288 + (tid - 544)]);
        }
        __syncthreads();                                           // B6

        // ---- phase 7: mix gate + l_read + next ctl; em slot write; bm update ----
        if (tid < 128) {
            int r = tid >> 5, w2 = tid & 31;
            float a = bmix[w2];
#pragma unroll
            for (int c = 0; c < 32; ++c) a += wmix_s[w2][c]      * emrd[r][c];
#pragma unroll
            for (int c = 0; c < 32; ++c) a += wmix_s[w2][32 + c] * bmrd[r][c];
            float g  = sigm(a);
            float rd = g * emrd[r][w2] + (1.f - g) * bmrd[r][w2];
            v[128 + tid] = rd;                 // l_read for next step's ctl
            out[outbase + 512 + tid] = rd;
        } else if (tid < 160) {
            em[slot][tid - 128] = itf[256 + (tid - 128)];   // deferred em_new slot write
        } else if (tid < 288) {
            int k = tid - 160;                 // next x into ctl
            if (t + 1 < 512) v[k] = x[((size_t)b*512 + t + 1)*128 + k];
        } else {
            for (int i2 = tid - 288; i2 < 2048; i2 += TPB - 288) {
                int n = i2 >> 5, w2 = i2 & 31;
                float ww = 0.25f * (sc[4][n] + sc[5][n] + sc[6][n] + sc[7][n]);
                bm[n][w2] = bm[n][w2] * (1.f - ww*ev[w2]) + ww*emer[w2];
            }
        }
        __syncthreads();                                           // B7 (loop)
    }
}

extern "C" void kernel_launch(void* const* d_in, const int* in_sizes, int n_in,
                              void* d_out, int out_size, void* d_ws, size_t ws_size,
                              hipStream_t stream)
{
    const float* x    = (const float*)d_in[0];
    const float* h0   = (const float*)d_in[1];
    const float* Wih0 = (const float*)d_in[2];
    const float* Whh0 = (const float*)d_in[3];
    const float* bih0 = (const float*)d_in[4];
    const float* bhh0 = (const float*)d_in[5];
    const float* Wih1 = (const float*)d_in[6];
    const float* Whh1 = (const float*)d_in[7];
    const float* bih1 = (const float*)d_in[8];
    const float* bhh1 = (const float*)d_in[9];
    const float* Wint = (const float*)d_in[10];
    const float* bint = (const float*)d_in[11];
    const float* Wmix = (const float*)d_in[12];
    const float* bmix = (const float*)d_in[13];
    ushort* ws  = (ushort*)d_ws;
    float*  out = (float*)d_out;

    if (ws_size < (size_t)WS_USHORTS * sizeof(ushort)) return;

    prep_kernel<<<(WS_USHORTS + 255)/256, 256, 0, stream>>>(Wih0, Whh0, Wih1, Whh1, Wint, ws);
    ebm_main<<<64, TPB, 0, stream>>>(x, h0, bih0, bhh0, bih1, bhh1, bint, Wmix, bmix, ws, out);
}